// Round 3
// baseline (220.522 us; speedup 1.0000x reference)
//
#include <hip/hip_runtime.h>
#include <hip/hip_bf16.h>

// DynamicWeights fused, LDS-resident (all 64 ch, bf16) with software-pipelined
// chunked staging: issue loads(chunk i+1) -> conv(chunk i) -> write(chunk i+1) -> barrier.
// x: (8,64,192,192) f32, conv_w: (9,64,3,3) f32, gamma: (1,) f32

constexpr int Nn = 8, Cc = 64, Hh = 192, Ww = 192;
constexpr int HW = Hh * Ww;
constexpr int TW = 64, TH = 4;
constexpr int LH = TH + 2;      // 6 rows incl. halo
constexpr int LWp = 68;         // col 1 = left halo, 2..65 interior, 66 = right halo (aligned)
constexpr int CH = 8;           // channels per staged chunk
constexpr int NCHK = Cc / CH;   // 8 chunks

__device__ __forceinline__ unsigned pk2(float a, float b) {
    union { __hip_bfloat16 h; unsigned short u; } ua, ub;
    ua.h = __float2bfloat16(a); ub.h = __float2bfloat16(b);
    return (unsigned)ua.u | ((unsigned)ub.u << 16);
}

__global__ __launch_bounds__(256, 3)
void dynw_fused(const float* __restrict__ x, const float* __restrict__ cw,
                const float* __restrict__ gamma, float* __restrict__ out)
{
    // 64*6*68*2 = 52224 B -> 3 blocks/CU (156672 <= 163840)
    __shared__ __hip_bfloat16 xs[Cc][LH][LWp];

    const int tid = threadIdx.x;
    const int tx = tid & 63, ty = tid >> 6;
    const int w0 = blockIdx.x * TW, h0 = blockIdx.y * TH, n = blockIdx.z;
    const float* __restrict__ xn = x + (size_t)n * Cc * HW;

    // ---- chunk-invariant staging geometry ----
    // interior: per chunk 8ch*6rows*16 float4 = 768 = 3/thread, aligned [w0,w0+64)
    int csub[3], rA[3], sg[3], roff[3]; bool rv[3];
#pragma unroll
    for (int j = 0; j < 3; ++j) {
        int gi = tid + j * 256;                 // 0..767
        csub[j] = gi / 96; int rem = gi - csub[j] * 96;   // 96 = 6*16
        rA[j] = rem >> 4; sg[j] = rem & 15;
        int gh = h0 + rA[j] - 1;
        rv[j] = (unsigned)gh < (unsigned)Hh;
        roff[j] = gh * Ww + w0 + sg[j] * 4;
    }
    // halo: 8ch*6rows*2 = 96 scalars, threads 0..95
    int hcs = 0, hr = 0, hcol = 1, hoff = 0; bool hv = false;
    const bool isH = tid < CH * LH * 2;
    if (isH) {
        hcs = tid / 12; int hrem = tid - hcs * 12;
        hr = hrem >> 1; int side = hrem & 1;
        int gh = h0 + hr - 1;
        int gw = side ? (w0 + TW) : (w0 - 1);
        hcol = side ? (LWp - 2) : 1;
        hv = ((unsigned)gh < (unsigned)Hh) && ((unsigned)gw < (unsigned)Ww);
        hoff = gh * Ww + gw;
    }

    auto issue = [&](int c0, float4 (&L)[3], float& hl) {
#pragma unroll
        for (int j = 0; j < 3; ++j) {
            const float* p = xn + (size_t)(c0 + csub[j]) * HW + roff[j];
            L[j] = rv[j] ? *(const float4*)p : make_float4(0.f, 0.f, 0.f, 0.f);
        }
        hl = (isH && hv) ? xn[(size_t)(c0 + hcs) * HW + hoff] : 0.f;
    };
    auto wrlds = [&](int c0, float4 (&L)[3], float hl) {
#pragma unroll
        for (int j = 0; j < 3; ++j) {
            unsigned* p = (unsigned*)&xs[c0 + csub[j]][rA[j]][2 + sg[j] * 4]; // 4B-aligned
            p[0] = pk2(L[j].x, L[j].y);
            p[1] = pk2(L[j].z, L[j].w);
        }
        if (isH) xs[c0 + hcs][hr][hcol] = __float2bfloat16(hl);
    };

    float dyn[9];
#pragma unroll
    for (int k = 0; k < 9; ++k) dyn[k] = 0.f;

    auto conv_chunk = [&](int c0) {
#pragma unroll
        for (int cc = 0; cc < CH; ++cc) {
            const int c = c0 + cc;
            float xv[9];
#pragma unroll
            for (int di = 0; di < 3; ++di)
#pragma unroll
                for (int dj = 0; dj < 3; ++dj)
                    xv[di * 3 + dj] = __bfloat162float(xs[c][ty + di][tx + 1 + dj]);
            const float* wc = cw + c * 9;          // wave-uniform -> s_loads
#pragma unroll
            for (int k = 0; k < 9; ++k) {
                const float* wk = wc + k * Cc * 9;
#pragma unroll
                for (int p9 = 0; p9 < 9; ++p9)
                    dyn[k] = fmaf(xv[p9], wk[p9], dyn[k]);
            }
        }
    };

    // ---- pipelined stage + conv ----
    {
        float4 A[3]; float hA;
        issue(0, A, hA);
        wrlds(0, A, hA);
    }
    __syncthreads();
    for (int chk = 0; chk < NCHK; ++chk) {
        float4 B[3]; float hB;
        if (chk + 1 < NCHK) issue((chk + 1) * CH, B, hB);   // loads fly under compute
        conv_chunk(chk * CH);
        if (chk + 1 < NCHK) { wrlds((chk + 1) * CH, B, hB); __syncthreads(); }
    }

    // ---- softmax over 9 taps (unnormalized; 1/sum folded into gamma) ----
    float m = dyn[0];
#pragma unroll
    for (int k = 1; k < 9; ++k) m = fmaxf(m, dyn[k]);
    float f[9]; float s = 0.f;
#pragma unroll
    for (int k = 0; k < 9; ++k) { f[k] = __expf(dyn[k] - m); s += f[k]; }
    const float gs = gamma[0] / s;

    // ---- combine + residual, all from LDS ----
    float* outp = out + (size_t)n * Cc * HW + (size_t)(h0 + ty) * Ww + (w0 + tx);
#pragma unroll 8
    for (int c = 0; c < Cc; ++c) {
        float acc = 0.f, xcen = 0.f;
#pragma unroll
        for (int di = 0; di < 3; ++di)
#pragma unroll
            for (int dj = 0; dj < 3; ++dj) {
                float v = __bfloat162float(xs[c][ty + di][tx + 1 + dj]);
                if (di == 1 && dj == 1) xcen = v;
                acc = fmaf(v, f[di * 3 + dj], acc);
            }
        outp[(size_t)c * HW] = fmaf(gs, acc, xcen);
    }
}

extern "C" void kernel_launch(void* const* d_in, const int* in_sizes, int n_in,
                              void* d_out, int out_size, void* d_ws, size_t ws_size,
                              hipStream_t stream) {
    const float* x  = (const float*)d_in[0];
    const float* cw = (const float*)d_in[1];
    const float* gm = (const float*)d_in[2];
    float* out = (float*)d_out;

    dim3 grid(Ww / TW, Hh / TH, Nn);   // (3, 48, 8) = 1152 blocks
    dim3 block(256);
    dynw_fused<<<grid, block, 0, stream>>>(x, cw, gm, out);
}

// Round 4
// 114.831 us; speedup vs baseline: 1.9204x; 1.9204x over previous
//
#include <hip/hip_runtime.h>

// DynamicWeights, two streaming kernels, no LDS, no barriers, all fp32.
// K1: conv3x3(64->9) + softmax, folds gamma/sum -> fs[9] planes in d_ws.
// K2: out = sum_p fs_p * x_p + x_center.
// x: (8,64,192,192) f32, conv_w: (9,64,3,3) f32, gamma: (1,) f32

constexpr int Nn = 8, Cc = 64, Hh = 192, Ww = 192;
constexpr int HW = Hh * Ww;
constexpr int NPX = Nn * HW;      // 294912
constexpr int TW = 64, TH = 4;    // 64x4 tile, 256 threads, 1 px/thread

__device__ __forceinline__ void tap_geom(int h, int w, int (&boff)[9], float (&msk)[9]) {
#pragma unroll
    for (int di = 0; di < 3; ++di)
#pragma unroll
        for (int dj = 0; dj < 3; ++dj) {
            int hh = h + di - 1, ww = w + dj - 1;
            bool v = ((unsigned)hh < (unsigned)Hh) && ((unsigned)ww < (unsigned)Ww);
            int hc = min(max(hh, 0), Hh - 1);
            int wc = min(max(ww, 0), Ww - 1);
            boff[di * 3 + dj] = (hc * Ww + wc) * 4;   // byte offset within a channel plane
            msk[di * 3 + dj] = v ? 1.f : 0.f;
        }
}

__global__ __launch_bounds__(256)
void k_conv(const float* __restrict__ x, const float* __restrict__ cw,
            const float* __restrict__ gamma, float* __restrict__ fs)
{
    const int tx = threadIdx.x & 63, ty = threadIdx.x >> 6;
    const int w = blockIdx.x * TW + tx;
    const int h = blockIdx.y * TH + ty;
    const int n = blockIdx.z;

    int boff[9]; float msk[9];
    tap_geom(h, w, boff, msk);

    const char* xn = (const char*)(x + (size_t)n * Cc * HW);

    float dyn[9];
#pragma unroll
    for (int k = 0; k < 9; ++k) dyn[k] = 0.f;

#pragma unroll 2
    for (int c = 0; c < Cc; ++c) {
        const char* xc = xn + (size_t)c * HW * 4;   // uniform base (SGPR)
        float xv[9];
#pragma unroll
        for (int p = 0; p < 9; ++p)
            xv[p] = *(const float*)(xc + boff[p]) * msk[p];
        const float* wc = cw + c * 9;               // uniform -> s_load
#pragma unroll
        for (int k = 0; k < 9; ++k) {
            const float* wk = wc + k * Cc * 9;
#pragma unroll
            for (int p = 0; p < 9; ++p)
                dyn[k] = fmaf(xv[p], wk[p], dyn[k]);
        }
    }

    // softmax over 9 taps; fold gamma/sum into the stored filter
    float m = dyn[0];
#pragma unroll
    for (int k = 1; k < 9; ++k) m = fmaxf(m, dyn[k]);
    float e[9]; float s = 0.f;
#pragma unroll
    for (int k = 0; k < 9; ++k) { e[k] = __expf(dyn[k] - m); s += e[k]; }
    const float gs = gamma[0] / s;

    const int pxflat = n * HW + h * Ww + w;
#pragma unroll
    for (int k = 0; k < 9; ++k)
        fs[(size_t)k * NPX + pxflat] = e[k] * gs;
}

__global__ __launch_bounds__(256)
void k_comb(const float* __restrict__ x, const float* __restrict__ fs,
            float* __restrict__ out)
{
    const int tx = threadIdx.x & 63, ty = threadIdx.x >> 6;
    const int w = blockIdx.x * TW + tx;
    const int h = blockIdx.y * TH + ty;
    const int n = blockIdx.z;

    int boff[9]; float msk[9];
    tap_geom(h, w, boff, msk);

    const int pxflat = n * HW + h * Ww + w;
    float f[9];
#pragma unroll
    for (int p = 0; p < 9; ++p)
        f[p] = fs[(size_t)p * NPX + pxflat] * msk[p];   // fold mask into filter once

    const char* xn = (const char*)(x + (size_t)n * Cc * HW);
    float* outp = out + (size_t)n * Cc * HW + h * Ww + w;

#pragma unroll 2
    for (int c = 0; c < Cc; ++c) {
        const char* xc = xn + (size_t)c * HW * 4;
        float acc = 0.f;
#pragma unroll
        for (int p = 0; p < 9; ++p)
            acc = fmaf(*(const float*)(xc + boff[p]), f[p], acc);
        const float xcen = *(const float*)(xc + boff[4]);  // center, always valid
        outp[(size_t)c * HW] = acc + xcen;
    }
}

extern "C" void kernel_launch(void* const* d_in, const int* in_sizes, int n_in,
                              void* d_out, int out_size, void* d_ws, size_t ws_size,
                              hipStream_t stream) {
    const float* x  = (const float*)d_in[0];
    const float* cw = (const float*)d_in[1];
    const float* gm = (const float*)d_in[2];
    float* out = (float*)d_out;
    float* fs  = (float*)d_ws;    // 9 * 294912 * 4 B = 10.6 MB scratch

    dim3 grid(Ww / TW, Hh / TH, Nn);   // (3, 48, 8) = 1152 blocks
    dim3 block(256);
    k_conv<<<grid, block, 0, stream>>>(x, cw, gm, fs);
    k_comb<<<grid, block, 0, stream>>>(x, fs, out);
}

// Round 5
// 110.480 us; speedup vs baseline: 1.9960x; 1.0394x over previous
//
#include <hip/hip_runtime.h>

// DynamicWeights, single fused streaming kernel: no LDS, no barriers, fp32.
// Phase A: conv3x3 (64ch -> 9 logits) per pixel, weights via wave-uniform s_loads.
// softmax over 9 taps, fold gamma/sum and border mask into f[9].
// Phase B: out[c] = sum_p f[p]*x[c,tap_p] + x[c,center]; taps re-hit L1/L2.
// x: (8,64,192,192) f32, conv_w: (9,64,3,3) f32, gamma: (1,) f32

constexpr int Nn = 8, Cc = 64, Hh = 192, Ww = 192;
constexpr int HW = Hh * Ww;
constexpr int TW = 64, TH = 4;    // 64x4 tile, 256 threads, 1 px/thread

__global__ __launch_bounds__(256)
void dynw_fused(const float* __restrict__ x, const float* __restrict__ cw,
                const float* __restrict__ gamma, float* __restrict__ out)
{
    const int tx = threadIdx.x & 63, ty = threadIdx.x >> 6;
    const int w = blockIdx.x * TW + tx;
    const int h = blockIdx.y * TH + ty;
    const int n = blockIdx.z;

    // tap geometry: clamped byte offsets + validity masks (branch-free)
    int boff[9]; float msk[9];
#pragma unroll
    for (int di = 0; di < 3; ++di)
#pragma unroll
        for (int dj = 0; dj < 3; ++dj) {
            int hh = h + di - 1, ww = w + dj - 1;
            bool v = ((unsigned)hh < (unsigned)Hh) && ((unsigned)ww < (unsigned)Ww);
            int hc = min(max(hh, 0), Hh - 1);
            int wc = min(max(ww, 0), Ww - 1);
            boff[di * 3 + dj] = (hc * Ww + wc) * 4;
            msk[di * 3 + dj] = v ? 1.f : 0.f;
        }

    const char* xn = (const char*)(x + (size_t)n * Cc * HW);

    // ---- Phase A: conv -> dyn[9] ----
    float dyn[9];
#pragma unroll
    for (int k = 0; k < 9; ++k) dyn[k] = 0.f;

#pragma unroll 4
    for (int c = 0; c < Cc; ++c) {
        const char* xc = xn + (size_t)c * HW * 4;   // wave-uniform base
        float xv[9];
#pragma unroll
        for (int p = 0; p < 9; ++p)
            xv[p] = *(const float*)(xc + boff[p]) * msk[p];
        const float* wc = cw + c * 9;               // wave-uniform -> s_load
#pragma unroll
        for (int k = 0; k < 9; ++k) {
            const float* wk = wc + k * Cc * 9;
#pragma unroll
            for (int p = 0; p < 9; ++p)
                dyn[k] = fmaf(xv[p], wk[p], dyn[k]);
        }
    }

    // ---- softmax over 9 taps; fold gamma/sum AND border mask into f ----
    float m = dyn[0];
#pragma unroll
    for (int k = 1; k < 9; ++k) m = fmaxf(m, dyn[k]);
    float f[9]; float s = 0.f;
#pragma unroll
    for (int k = 0; k < 9; ++k) { f[k] = __expf(dyn[k] - m); s += f[k]; }
    const float gs = gamma[0] / s;
#pragma unroll
    for (int k = 0; k < 9; ++k) f[k] = f[k] * gs * msk[k];

    // ---- Phase B: weighted combine + residual; taps re-hit L1/L2 ----
    float* outp = out + (size_t)n * Cc * HW + h * Ww + w;
#pragma unroll 4
    for (int c = 0; c < Cc; ++c) {
        const char* xc = xn + (size_t)c * HW * 4;
        float acc = 0.f;
#pragma unroll
        for (int p = 0; p < 9; ++p)
            acc = fmaf(*(const float*)(xc + boff[p]), f[p], acc);
        const float xcen = *(const float*)(xc + boff[4]);  // center, always valid
        outp[(size_t)c * HW] = acc + xcen;
    }
}

extern "C" void kernel_launch(void* const* d_in, const int* in_sizes, int n_in,
                              void* d_out, int out_size, void* d_ws, size_t ws_size,
                              hipStream_t stream) {
    const float* x  = (const float*)d_in[0];
    const float* cw = (const float*)d_in[1];
    const float* gm = (const float*)d_in[2];
    float* out = (float*)d_out;

    dim3 grid(Ww / TW, Hh / TH, Nn);   // (3, 48, 8) = 1152 blocks
    dim3 block(256);
    dynw_fused<<<grid, block, 0, stream>>>(x, cw, gm, out);
}